// Round 1
// baseline (882.758 us; speedup 1.0000x reference)
//
#include <hip/hip_runtime.h>
#include <math.h>

#define SQ2F 1.41421356237309515f

typedef float f32x4 __attribute__((ext_vector_type(4)));
typedef _Float16 f16x8 __attribute__((ext_vector_type(8)));

union Frag {
  uint4 u;
  f16x8 h;
  _Float16 f[8];
};

__device__ __forceinline__ float silu_f(float x) {
  return x / (1.0f + __expf(-x));
}

// workspace element offsets (fp16 elements)
#define W1T_OFF 0         // [384][384]  w1t[o][k] = w1[k][o]
#define W2T_OFF 147456    // [640][384]  w2t[o][k] = w2[k][o]  (cols 640..767 dead)
#define WST_OFF 393216    // [128][384]
#define WVT_OFF 442368    // [128][256]
#define WTOTAL  475136

__global__ void prep_weights_kernel(const float* __restrict__ w1,
                                    const float* __restrict__ w2,
                                    const float* __restrict__ wsm,
                                    const float* __restrict__ wv,
                                    _Float16* __restrict__ wt) {
  int idx = blockIdx.x * blockDim.x + threadIdx.x;
  if (idx >= WTOTAL) return;
  float v;
  if (idx < W2T_OFF) {
    int o = idx / 384, k = idx - o * 384;
    v = w1[k * 384 + o];
  } else if (idx < WST_OFF) {
    int t = idx - W2T_OFF;
    int o = t / 384, k = t - o * 384;
    v = w2[k * 768 + o];
  } else if (idx < WVT_OFF) {
    int t = idx - WST_OFF;
    int o = t / 384, k = t - o * 384;
    v = wsm[k * 128 + o];
  } else {
    int t = idx - WVT_OFF;
    int o = t / 256, k = t - o * 256;
    v = wv[k * 128 + o];
  }
  wt[idx] = (_Float16)v;
}

// LDS layout (byte offsets). Row strides padded so row-to-row bank shift = 4
// dwords (2-way max conflict on b128 reads, which is free per m136).
#define SC_OFF    0        // scal  [64][392] f16 (cols 0-127 s, 128-255 ss, 256-383 vv; gated in place in phase 2)
#define SRAW_OFF  50176    // raw s [64][136] f16
#define H1_OFF    67584    // union: h1 [64][392] f16  OR  vp [3][64][136] f16 (52224 B region)
#define GVB_OFF   119808   // gv gates [64][264] f16
#define RED_OFF   153600   // 192 floats: rsum[64], rsq[64], vsq[64]
#define LDS_BYTES 154368

__launch_bounds__(512, 2)
__global__ void fused_kernel(const float* __restrict__ x,
                             const _Float16* __restrict__ wt,
                             float* __restrict__ out, int n) {
  extern __shared__ __align__(16) char smem[];
  _Float16* sc   = (_Float16*)(smem + SC_OFF);
  _Float16* sraw = (_Float16*)(smem + SRAW_OFF);
  _Float16* h1   = (_Float16*)(smem + H1_OFF);
  _Float16* vp   = (_Float16*)(smem + H1_OFF);   // alias, used after h1 is dead
  _Float16* gvb  = (_Float16*)(smem + GVB_OFF);
  float*    red  = (float*)(smem + RED_OFF);

  const int rb   = blockIdx.x * 64;
  const int tid  = threadIdx.x;
  const int wv   = tid >> 6;     // wave 0..7
  const int lane = tid & 63;
  const int l15  = lane & 15;
  const int q    = lane >> 4;    // 0..3

  const _Float16* w1t = wt + W1T_OFF;
  const _Float16* w2t = wt + W2T_OFF;
  const _Float16* wst = wt + WST_OFF;
  const _Float16* wvt = wt + WVT_OFF;

  // ---------------- Phase 0: load x tile, build scal features + sraw ----------
  {
    int row = tid >> 3;          // 0..63
    int j   = tid & 7;           // 8 threads per row
    int grow = rb + row;
    bool valid = grow < n;
    const float* xr = x + (size_t)grow * 512;
    float sv[16];
#pragma unroll
    for (int c4 = 0; c4 < 4; ++c4) {
      float4 f = valid ? ((const float4*)(xr + j * 16))[c4] : make_float4(0.f, 0.f, 0.f, 0.f);
      sv[c4 * 4 + 0] = f.x; sv[c4 * 4 + 1] = f.y; sv[c4 * 4 + 2] = f.z; sv[c4 * 4 + 3] = f.w;
    }
#pragma unroll
    for (int c = 0; c < 16; ++c) {
      _Float16 hv = (_Float16)sv[c];
      sraw[row * 136 + j * 16 + c] = hv;
      sc[row * 392 + j * 16 + c] = hv;
      sc[row * 392 + 128 + j * 16 + c] = (_Float16)(sv[c] * sv[c]);
    }
    float vf[48];
#pragma unroll
    for (int c4 = 0; c4 < 12; ++c4) {
      float4 f = valid ? ((const float4*)(xr + 128 + j * 48))[c4] : make_float4(0.f, 0.f, 0.f, 0.f);
      vf[c4 * 4 + 0] = f.x; vf[c4 * 4 + 1] = f.y; vf[c4 * 4 + 2] = f.z; vf[c4 * 4 + 3] = f.w;
    }
#pragma unroll
    for (int u = 0; u < 16; ++u) {
      float a = vf[u * 3 + 0], b = vf[u * 3 + 1], c = vf[u * 3 + 2];
      sc[row * 392 + 256 + j * 16 + u] = (_Float16)(a * a + b * b + c * c);
    }
  }
  __syncthreads();

  // ---------------- Phase 1: h1 = silu(scal @ W1), wave strip = 48 cols -------
  {
    f32x4 acc[4][3];
#pragma unroll
    for (int rt = 0; rt < 4; ++rt)
#pragma unroll
      for (int ct = 0; ct < 3; ++ct) acc[rt][ct] = (f32x4){0.f, 0.f, 0.f, 0.f};
#pragma unroll
    for (int kk = 0; kk < 12; ++kk) {
      int koff = kk * 32 + q * 8;
      Frag a[4], b[3];
#pragma unroll
      for (int rt = 0; rt < 4; ++rt)
        a[rt].u = *(const uint4*)(sc + (rt * 16 + l15) * 392 + koff);
#pragma unroll
      for (int ct = 0; ct < 3; ++ct) {
        int nn = wv * 48 + ct * 16 + l15;
        b[ct].u = *(const uint4*)(w1t + nn * 384 + koff);
      }
#pragma unroll
      for (int rt = 0; rt < 4; ++rt)
#pragma unroll
        for (int ct = 0; ct < 3; ++ct)
          acc[rt][ct] = __builtin_amdgcn_mfma_f32_16x16x32_f16(a[rt].h, b[ct].h, acc[rt][ct], 0, 0, 0);
    }
#pragma unroll
    for (int rt = 0; rt < 4; ++rt)
#pragma unroll
      for (int ct = 0; ct < 3; ++ct)
#pragma unroll
        for (int r = 0; r < 4; ++r) {
          int row = rt * 16 + q * 4 + r;
          int col = wv * 48 + ct * 16 + l15;
          h1[row * 392 + col] = (_Float16)silu_f(acc[rt][ct][r]);
        }
  }
  __syncthreads();

  // ---------------- Phase 2: gates = silu(h1 @ W2[:, :640]); apply gs, stash gv
  {
    f32x4 acc[4][5];
#pragma unroll
    for (int rt = 0; rt < 4; ++rt)
#pragma unroll
      for (int ct = 0; ct < 5; ++ct) acc[rt][ct] = (f32x4){0.f, 0.f, 0.f, 0.f};
#pragma unroll
    for (int kk = 0; kk < 12; ++kk) {
      int koff = kk * 32 + q * 8;
      Frag a[4], b[5];
#pragma unroll
      for (int rt = 0; rt < 4; ++rt)
        a[rt].u = *(const uint4*)(h1 + (rt * 16 + l15) * 392 + koff);
#pragma unroll
      for (int ct = 0; ct < 5; ++ct) {
        int nn = wv * 80 + ct * 16 + l15;
        b[ct].u = *(const uint4*)(w2t + nn * 384 + koff);
      }
#pragma unroll
      for (int rt = 0; rt < 4; ++rt)
#pragma unroll
        for (int ct = 0; ct < 5; ++ct)
          acc[rt][ct] = __builtin_amdgcn_mfma_f32_16x16x32_f16(a[rt].h, b[ct].h, acc[rt][ct], 0, 0, 0);
    }
#pragma unroll
    for (int rt = 0; rt < 4; ++rt)
#pragma unroll
      for (int ct = 0; ct < 5; ++ct) {
        int colbase = wv * 80 + ct * 16;   // tile-uniform; 384 boundary is 16-aligned
#pragma unroll
        for (int r = 0; r < 4; ++r) {
          int row = rt * 16 + q * 4 + r;
          int col = colbase + l15;
          float g = silu_f(acc[rt][ct][r]);
          if (colbase < 384) {
            float s0 = (float)sc[row * 392 + col];
            sc[row * 392 + col] = (_Float16)(s0 * g);
          } else {
            gvb[row * 264 + (col - 384)] = (_Float16)g;
          }
        }
      }
  }
  __syncthreads();

  // ---------------- Phase 2.5: reload v into vp (h1's space); zero reductions -
  {
    int row = tid >> 3;
    int j   = tid & 7;
    int grow = rb + row;
    bool valid = grow < n;
    const float* xr = x + (size_t)grow * 512 + 128 + j * 48;
    float vf[48];
#pragma unroll
    for (int c4 = 0; c4 < 12; ++c4) {
      float4 f = valid ? ((const float4*)xr)[c4] : make_float4(0.f, 0.f, 0.f, 0.f);
      vf[c4 * 4 + 0] = f.x; vf[c4 * 4 + 1] = f.y; vf[c4 * 4 + 2] = f.z; vf[c4 * 4 + 3] = f.w;
    }
#pragma unroll
    for (int u = 0; u < 16; ++u)
#pragma unroll
      for (int i = 0; i < 3; ++i)
        vp[i * 8704 + row * 136 + j * 16 + u] = (_Float16)vf[u * 3 + i];
    if (tid < 192) red[tid] = 0.f;
  }
  __syncthreads();

  // ---------------- Phase 3a: out_s = (scal*gs) @ Ws, wave strip = 16 cols ----
  f32x4 os[4];
#pragma unroll
  for (int rt = 0; rt < 4; ++rt) os[rt] = (f32x4){0.f, 0.f, 0.f, 0.f};
#pragma unroll
  for (int kk = 0; kk < 12; ++kk) {
    int koff = kk * 32 + q * 8;
    Frag a[4], b;
#pragma unroll
    for (int rt = 0; rt < 4; ++rt)
      a[rt].u = *(const uint4*)(sc + (rt * 16 + l15) * 392 + koff);
    int nn = wv * 16 + l15;
    b.u = *(const uint4*)(wst + nn * 384 + koff);
#pragma unroll
    for (int rt = 0; rt < 4; ++rt)
      os[rt] = __builtin_amdgcn_mfma_f32_16x16x32_f16(a[rt].h, b.h, os[rt], 0, 0, 0);
  }

  // ---------------- Phase 3b: out_v[i] = (vecs*gv) @ Wv ----------------------
  f32x4 ov[3][4];
#pragma unroll
  for (int i = 0; i < 3; ++i)
#pragma unroll
    for (int rt = 0; rt < 4; ++rt) ov[i][rt] = (f32x4){0.f, 0.f, 0.f, 0.f};
#pragma unroll
  for (int kk = 0; kk < 8; ++kk) {
    int koff = kk * 32 + q * 8;   // u index 0..255
    int um = koff & 127;
    Frag bv;
    {
      int nn = wv * 16 + l15;
      bv.u = *(const uint4*)(wvt + nn * 256 + koff);
    }
#pragma unroll
    for (int rt = 0; rt < 4; ++rt) {
      int row = rt * 16 + l15;    // A-layout: row = lane&15
      Frag gv8;
      gv8.u = *(const uint4*)(gvb + row * 264 + koff);
      float m[8];
      if (kk < 4) {
#pragma unroll
        for (int j = 0; j < 8; ++j) m[j] = (float)gv8.f[j];
      } else {
        Frag s8;
        s8.u = *(const uint4*)(sraw + row * 136 + um);
#pragma unroll
        for (int j = 0; j < 8; ++j) m[j] = SQ2F * (float)s8.f[j] * (float)gv8.f[j];
      }
      Frag av[3];
#pragma unroll
      for (int i = 0; i < 3; ++i) {
        Frag v8;
        v8.u = *(const uint4*)(vp + i * 8704 + row * 136 + um);
#pragma unroll
        for (int j = 0; j < 8; ++j) av[i].f[j] = (_Float16)((float)v8.f[j] * m[j]);
      }
#pragma unroll
      for (int i = 0; i < 3; ++i)
        ov[i][rt] = __builtin_amdgcn_mfma_f32_16x16x32_f16(av[i].h, bv.h, ov[i][rt], 0, 0, 0);
    }
  }

  // ---------------- Epilogue: residuals, row stats, normalize, store ---------
#pragma unroll
  for (int rt = 0; rt < 4; ++rt) {
#pragma unroll
    for (int r = 0; r < 4; ++r) {
      int row = rt * 16 + q * 4 + r;   // C-layout row
      int col = wv * 16 + l15;
      float o = os[rt][r] + (float)sraw[row * 136 + col];
      os[rt][r] = o;
      float v0 = ov[0][rt][r] + (float)vp[0 * 8704 + row * 136 + col];
      float v1 = ov[1][rt][r] + (float)vp[1 * 8704 + row * 136 + col];
      float v2 = ov[2][rt][r] + (float)vp[2 * 8704 + row * 136 + col];
      ov[0][rt][r] = v0; ov[1][rt][r] = v1; ov[2][rt][r] = v2;
      float so = o, sq = o * o, vq = v0 * v0 + v1 * v1 + v2 * v2;
#pragma unroll
      for (int mm = 1; mm < 16; mm <<= 1) {
        so += __shfl_xor(so, mm, 64);
        sq += __shfl_xor(sq, mm, 64);
        vq += __shfl_xor(vq, mm, 64);
      }
      if (l15 == 0) {
        atomicAdd(&red[row], so);
        atomicAdd(&red[64 + row], sq);
        atomicAdd(&red[128 + row], vq);
      }
    }
  }
  __syncthreads();
#pragma unroll
  for (int rt = 0; rt < 4; ++rt) {
#pragma unroll
    for (int r = 0; r < 4; ++r) {
      int row = rt * 16 + q * 4 + r;
      int grow = rb + row;
      if (grow < n) {
        int col = wv * 16 + l15;
        float mean = red[row] * (1.f / 128.f);
        float ms = red[64 + row] * (1.f / 128.f) - mean * mean;
        float rinv = 1.f / (sqrtf(fmaxf(ms, 0.f)) + 1e-6f);
        float vn = sqrtf(red[128 + row] * (1.f / 128.f));
        float vinv = 1.f / (vn + 1e-6f);
        float* orow = out + (size_t)grow * 512;
        orow[col] = (os[rt][r] - mean) * rinv;
        orow[128 + col * 3 + 0] = ov[0][rt][r] * vinv;
        orow[128 + col * 3 + 1] = ov[1][rt][r] * vinv;
        orow[128 + col * 3 + 2] = ov[2][rt][r] * vinv;
      }
    }
  }
}

extern "C" void kernel_launch(void* const* d_in, const int* in_sizes, int n_in,
                              void* d_out, int out_size, void* d_ws, size_t ws_size,
                              hipStream_t stream) {
  const float* x   = (const float*)d_in[0];
  const float* w1  = (const float*)d_in[1];
  const float* w2  = (const float*)d_in[2];
  const float* wsm = (const float*)d_in[3];
  const float* wv  = (const float*)d_in[4];
  float* out = (float*)d_out;
  int n = in_sizes[0] / 512;
  _Float16* wt = (_Float16*)d_ws;

  // >64KB dynamic LDS needs the attribute opt-in; idempotent, capture-safe.
  hipFuncSetAttribute((const void*)fused_kernel,
                      hipFuncAttributeMaxDynamicSharedMemorySize, LDS_BYTES);

  prep_weights_kernel<<<(WTOTAL + 255) / 256, 256, 0, stream>>>(w1, w2, wsm, wv, wt);
  int grid = (n + 63) / 64;
  fused_kernel<<<grid, 512, LDS_BYTES, stream>>>(x, wt, out, n);
}

// Round 2
// 682.238 us; speedup vs baseline: 1.2939x; 1.2939x over previous
//
#include <hip/hip_runtime.h>
#include <math.h>

#define SQ2F 1.41421356237309515f

typedef float f32x4 __attribute__((ext_vector_type(4)));
typedef _Float16 f16x8 __attribute__((ext_vector_type(8)));

union Frag {
  uint4 u;
  f16x8 h;
  _Float16 f[8];
};

__device__ __forceinline__ float silu_f(float x) {
  return x / (1.0f + __expf(-x));
}

// workspace element offsets (fp16 elements)
#define W1T_OFF 0         // [384][384]  w1t[o][k] = w1[k][o]
#define W2T_OFF 147456    // [640][384]  w2t[o][k] = w2[k][o]  (cols 640..767 dead)
#define WST_OFF 393216    // [128][384]
#define WVT_OFF 442368    // [128][256]
#define WTOTAL  475136

__global__ void prep_weights_kernel(const float* __restrict__ w1,
                                    const float* __restrict__ w2,
                                    const float* __restrict__ wsm,
                                    const float* __restrict__ wv,
                                    _Float16* __restrict__ wt) {
  int idx = blockIdx.x * blockDim.x + threadIdx.x;
  if (idx >= WTOTAL) return;
  float v;
  if (idx < W2T_OFF) {
    int o = idx / 384, k = idx - o * 384;
    v = w1[k * 384 + o];
  } else if (idx < WST_OFF) {
    int t = idx - W2T_OFF;
    int o = t / 384, k = t - o * 384;
    v = w2[k * 768 + o];
  } else if (idx < WVT_OFF) {
    int t = idx - WST_OFF;
    int o = t / 384, k = t - o * 384;
    v = wsm[k * 128 + o];
  } else {
    int t = idx - WVT_OFF;
    int o = t / 256, k = t - o * 256;
    v = wv[k * 128 + o];
  }
  wt[idx] = (_Float16)v;
}

// LDS layout (byte offsets), 32-row tile. 77184 B total -> 2 blocks/CU.
// Strides padded so row-to-row bank shift = 4 dwords (2-way max on b128 = free).
#define SC_OFF    0        // scal [32][392] f16 (s|ss|vv); gated in place in P2
#define SRAW_OFF  25088    // raw s [32][136] f16
#define VA_OFF    33792    // union: h1 [32][392] f16 (P1/P2)  OR  va half [3][32][136] f16
#define M_OFF     59904    // gate multipliers m [32][264] f16 (u=0..255)
#define RED_OFF   76800    // 96 floats: rsum[32], rsq[32], vsq[32]
#define LDS_BYTES 77184

__launch_bounds__(512, 4)
__global__ void fused_kernel(const float* __restrict__ x,
                             const _Float16* __restrict__ wt,
                             float* __restrict__ out, int n) {
  extern __shared__ __align__(16) char smem[];
  _Float16* sc   = (_Float16*)(smem + SC_OFF);
  _Float16* sraw = (_Float16*)(smem + SRAW_OFF);
  _Float16* h1   = (_Float16*)(smem + VA_OFF);
  _Float16* va   = (_Float16*)(smem + VA_OFF);   // alias; used after h1 dead
  _Float16* mbuf = (_Float16*)(smem + M_OFF);
  float*    red  = (float*)(smem + RED_OFF);

  const int rb   = blockIdx.x * 32;
  const int tid  = threadIdx.x;
  const int wv   = tid >> 6;     // wave 0..7
  const int lane = tid & 63;
  const int l15  = lane & 15;
  const int q    = lane >> 4;    // 0..3

  const _Float16* w1t = wt + W1T_OFF;
  const _Float16* w2t = wt + W2T_OFF;
  const _Float16* wst = wt + WST_OFF;
  const _Float16* wvt = wt + WVT_OFF;

  const int lrow = tid >> 4;     // loader row 0..31 (16 threads/row)
  const int lj   = tid & 15;

  // v planes held in registers from phase 0 to phase 2.5 (8 u's x 3 planes)
  Frag vh[3];

  // ---------------- Phase 0: load x tile, build scal features ----------------
  {
    int grow = rb + lrow;
    bool valid = grow < n;
    const float* xr = x + (size_t)grow * 512;
    float sv[8];
#pragma unroll
    for (int c4 = 0; c4 < 2; ++c4) {
      float4 f = valid ? ((const float4*)(xr + lj * 8))[c4] : make_float4(0.f, 0.f, 0.f, 0.f);
      sv[c4 * 4 + 0] = f.x; sv[c4 * 4 + 1] = f.y; sv[c4 * 4 + 2] = f.z; sv[c4 * 4 + 3] = f.w;
    }
#pragma unroll
    for (int c = 0; c < 8; ++c) {
      _Float16 hv = (_Float16)sv[c];
      sraw[lrow * 136 + lj * 8 + c] = hv;
      sc[lrow * 392 + lj * 8 + c] = hv;
      sc[lrow * 392 + 128 + lj * 8 + c] = (_Float16)(sv[c] * sv[c]);
    }
    float vf[24];
#pragma unroll
    for (int c4 = 0; c4 < 6; ++c4) {
      float4 f = valid ? ((const float4*)(xr + 128 + lj * 24))[c4] : make_float4(0.f, 0.f, 0.f, 0.f);
      vf[c4 * 4 + 0] = f.x; vf[c4 * 4 + 1] = f.y; vf[c4 * 4 + 2] = f.z; vf[c4 * 4 + 3] = f.w;
    }
#pragma unroll
    for (int u = 0; u < 8; ++u) {
      float a = vf[u * 3 + 0], b = vf[u * 3 + 1], c = vf[u * 3 + 2];
      vh[0].f[u] = (_Float16)a; vh[1].f[u] = (_Float16)b; vh[2].f[u] = (_Float16)c;
      sc[lrow * 392 + 256 + lj * 8 + u] = (_Float16)(a * a + b * b + c * c);
    }
  }
  __syncthreads();

  // ---------------- Phase 1: h1 = silu(scal @ W1), wave strip = 48 cols -------
  {
    f32x4 acc[2][3];
#pragma unroll
    for (int rt = 0; rt < 2; ++rt)
#pragma unroll
      for (int ct = 0; ct < 3; ++ct) acc[rt][ct] = (f32x4){0.f, 0.f, 0.f, 0.f};
#pragma unroll
    for (int kk = 0; kk < 12; ++kk) {
      int koff = kk * 32 + q * 8;
      Frag a[2], b[3];
#pragma unroll
      for (int rt = 0; rt < 2; ++rt)
        a[rt].u = *(const uint4*)(sc + (rt * 16 + l15) * 392 + koff);
#pragma unroll
      for (int ct = 0; ct < 3; ++ct) {
        int nn = wv * 48 + ct * 16 + l15;
        b[ct].u = *(const uint4*)(w1t + nn * 384 + koff);
      }
#pragma unroll
      for (int rt = 0; rt < 2; ++rt)
#pragma unroll
        for (int ct = 0; ct < 3; ++ct)
          acc[rt][ct] = __builtin_amdgcn_mfma_f32_16x16x32_f16(a[rt].h, b[ct].h, acc[rt][ct], 0, 0, 0);
    }
#pragma unroll
    for (int rt = 0; rt < 2; ++rt)
#pragma unroll
      for (int ct = 0; ct < 3; ++ct)
#pragma unroll
        for (int r = 0; r < 4; ++r) {
          int row = rt * 16 + q * 4 + r;
          int col = wv * 48 + ct * 16 + l15;
          h1[row * 392 + col] = (_Float16)silu_f(acc[rt][ct][r]);
        }
  }
  __syncthreads();

  // ---------------- Phase 2: gates = silu(h1 @ W2[:, :640]) -------------------
  // cols 0..383   -> gate sc in place (gs)
  // cols 384..511 -> mbuf[u] = g                (v gates,  u = col-384)
  // cols 512..639 -> mbuf[u] = sqrt2*s*g        (sv gates, u = col-384)
  {
    f32x4 acc[2][5];
#pragma unroll
    for (int rt = 0; rt < 2; ++rt)
#pragma unroll
      for (int ct = 0; ct < 5; ++ct) acc[rt][ct] = (f32x4){0.f, 0.f, 0.f, 0.f};
#pragma unroll
    for (int kk = 0; kk < 12; ++kk) {
      int koff = kk * 32 + q * 8;
      Frag a[2], b[5];
#pragma unroll
      for (int rt = 0; rt < 2; ++rt)
        a[rt].u = *(const uint4*)(h1 + (rt * 16 + l15) * 392 + koff);
#pragma unroll
      for (int ct = 0; ct < 5; ++ct) {
        int nn = wv * 80 + ct * 16 + l15;
        b[ct].u = *(const uint4*)(w2t + nn * 384 + koff);
      }
#pragma unroll
      for (int rt = 0; rt < 2; ++rt)
#pragma unroll
        for (int ct = 0; ct < 5; ++ct)
          acc[rt][ct] = __builtin_amdgcn_mfma_f32_16x16x32_f16(a[rt].h, b[ct].h, acc[rt][ct], 0, 0, 0);
    }
#pragma unroll
    for (int rt = 0; rt < 2; ++rt)
#pragma unroll
      for (int ct = 0; ct < 5; ++ct) {
        int colbase = wv * 80 + ct * 16;   // tile-uniform; 384/512 are 16-aligned
#pragma unroll
        for (int r = 0; r < 4; ++r) {
          int row = rt * 16 + q * 4 + r;
          int col = colbase + l15;
          float g = silu_f(acc[rt][ct][r]);
          if (colbase < 384) {
            float s0 = (float)sc[row * 392 + col];
            sc[row * 392 + col] = (_Float16)(s0 * g);
          } else if (colbase < 512) {
            mbuf[row * 264 + (col - 384)] = (_Float16)g;
          } else {
            float s0 = (float)sraw[row * 136 + (col - 512)];
            mbuf[row * 264 + (col - 384)] = (_Float16)(SQ2F * s0 * g);
          }
        }
      }
  }
  __syncthreads();

  // ---------------- Phase 2.5a: va (u<128) = v * m, from registers ------------
  {
    Frag m8;
    m8.u = *(const uint4*)(mbuf + lrow * 264 + lj * 8);
#pragma unroll
    for (int i = 0; i < 3; ++i) {
      Frag o; o.h = vh[i].h * m8.h;
      *(uint4*)(va + i * 4352 + lrow * 136 + lj * 8) = o.u;
    }
  }
  __syncthreads();

  // ---------------- Phase 3a: out_s = (scal*gs) @ Ws --------------------------
  f32x4 os[2];
#pragma unroll
  for (int rt = 0; rt < 2; ++rt) os[rt] = (f32x4){0.f, 0.f, 0.f, 0.f};
#pragma unroll
  for (int kk = 0; kk < 12; ++kk) {
    int koff = kk * 32 + q * 8;
    Frag a[2], b;
#pragma unroll
    for (int rt = 0; rt < 2; ++rt)
      a[rt].u = *(const uint4*)(sc + (rt * 16 + l15) * 392 + koff);
    int nn = wv * 16 + l15;
    b.u = *(const uint4*)(wst + nn * 384 + koff);
#pragma unroll
    for (int rt = 0; rt < 2; ++rt)
      os[rt] = __builtin_amdgcn_mfma_f32_16x16x32_f16(a[rt].h, b.h, os[rt], 0, 0, 0);
  }

  // ---------------- Phase 3b half 1: u 0..127 ---------------------------------
  f32x4 ov[3][2];
#pragma unroll
  for (int i = 0; i < 3; ++i)
#pragma unroll
    for (int rt = 0; rt < 2; ++rt) ov[i][rt] = (f32x4){0.f, 0.f, 0.f, 0.f};
#pragma unroll
  for (int kk = 0; kk < 4; ++kk) {
    int koff = kk * 32 + q * 8;
    Frag bv;
    bv.u = *(const uint4*)(wvt + (wv * 16 + l15) * 256 + koff);
#pragma unroll
    for (int rt = 0; rt < 2; ++rt) {
      Frag av[3];
#pragma unroll
      for (int i = 0; i < 3; ++i)
        av[i].u = *(const uint4*)(va + i * 4352 + (rt * 16 + l15) * 136 + koff);
#pragma unroll
      for (int i = 0; i < 3; ++i)
        ov[i][rt] = __builtin_amdgcn_mfma_f32_16x16x32_f16(av[i].h, bv.h, ov[i][rt], 0, 0, 0);
    }
  }
  __syncthreads();   // va half-1 consumed

  // ---------------- Phase 2.5b: va (u 128..255) = v * m2; zero red ------------
  {
    Frag m8;
    m8.u = *(const uint4*)(mbuf + lrow * 264 + 128 + lj * 8);
#pragma unroll
    for (int i = 0; i < 3; ++i) {
      Frag o; o.h = vh[i].h * m8.h;
      *(uint4*)(va + i * 4352 + lrow * 136 + lj * 8) = o.u;
    }
    if (tid < 96) red[tid] = 0.f;
  }
  __syncthreads();

  // ---------------- Phase 3b half 2: u 128..255 -------------------------------
#pragma unroll
  for (int kk = 0; kk < 4; ++kk) {
    int koff = kk * 32 + q * 8;
    Frag bv;
    bv.u = *(const uint4*)(wvt + (wv * 16 + l15) * 256 + 128 + koff);
#pragma unroll
    for (int rt = 0; rt < 2; ++rt) {
      Frag av[3];
#pragma unroll
      for (int i = 0; i < 3; ++i)
        av[i].u = *(const uint4*)(va + i * 4352 + (rt * 16 + l15) * 136 + koff);
#pragma unroll
      for (int i = 0; i < 3; ++i)
        ov[i][rt] = __builtin_amdgcn_mfma_f32_16x16x32_f16(av[i].h, bv.h, ov[i][rt], 0, 0, 0);
    }
  }

  // ---------------- Epilogue: residuals, row stats, normalize, store ---------
#pragma unroll
  for (int rt = 0; rt < 2; ++rt) {
#pragma unroll
    for (int r = 0; r < 4; ++r) {
      int row = rt * 16 + q * 4 + r;   // C-layout row
      int col = wv * 16 + l15;
      int grow = rb + row;
      float o = os[rt][r] + (float)sraw[row * 136 + col];
      os[rt][r] = o;
      float rv0 = 0.f, rv1 = 0.f, rv2 = 0.f;
      if (grow < n) {
        const float* xv = x + (size_t)grow * 512 + 128 + col * 3;
        rv0 = xv[0]; rv1 = xv[1]; rv2 = xv[2];
      }
      float v0 = ov[0][rt][r] + rv0;
      float v1 = ov[1][rt][r] + rv1;
      float v2 = ov[2][rt][r] + rv2;
      ov[0][rt][r] = v0; ov[1][rt][r] = v1; ov[2][rt][r] = v2;
      float so = o, sq = o * o, vq = v0 * v0 + v1 * v1 + v2 * v2;
#pragma unroll
      for (int mm = 1; mm < 16; mm <<= 1) {
        so += __shfl_xor(so, mm, 64);
        sq += __shfl_xor(sq, mm, 64);
        vq += __shfl_xor(vq, mm, 64);
      }
      if (l15 == 0) {
        atomicAdd(&red[row], so);
        atomicAdd(&red[32 + row], sq);
        atomicAdd(&red[64 + row], vq);
      }
    }
  }
  __syncthreads();
#pragma unroll
  for (int rt = 0; rt < 2; ++rt) {
#pragma unroll
    for (int r = 0; r < 4; ++r) {
      int row = rt * 16 + q * 4 + r;
      int grow = rb + row;
      if (grow < n) {
        int col = wv * 16 + l15;
        float mean = red[row] * (1.f / 128.f);
        float ms = red[32 + row] * (1.f / 128.f) - mean * mean;
        float rinv = 1.f / (sqrtf(fmaxf(ms, 0.f)) + 1e-6f);
        float vn = sqrtf(red[64 + row] * (1.f / 128.f));
        float vinv = 1.f / (vn + 1e-6f);
        float* orow = out + (size_t)grow * 512;
        orow[col] = (os[rt][r] - mean) * rinv;
        orow[128 + col * 3 + 0] = ov[0][rt][r] * vinv;
        orow[128 + col * 3 + 1] = ov[1][rt][r] * vinv;
        orow[128 + col * 3 + 2] = ov[2][rt][r] * vinv;
      }
    }
  }
}

extern "C" void kernel_launch(void* const* d_in, const int* in_sizes, int n_in,
                              void* d_out, int out_size, void* d_ws, size_t ws_size,
                              hipStream_t stream) {
  const float* x   = (const float*)d_in[0];
  const float* w1  = (const float*)d_in[1];
  const float* w2  = (const float*)d_in[2];
  const float* wsm = (const float*)d_in[3];
  const float* wv  = (const float*)d_in[4];
  float* out = (float*)d_out;
  int n = in_sizes[0] / 512;
  _Float16* wt = (_Float16*)d_ws;

  // >64KB dynamic LDS needs the attribute opt-in; idempotent, capture-safe.
  hipFuncSetAttribute((const void*)fused_kernel,
                      hipFuncAttributeMaxDynamicSharedMemorySize, LDS_BYTES);

  prep_weights_kernel<<<(WTOTAL + 255) / 256, 256, 0, stream>>>(w1, w2, wsm, wv, wt);
  int grid = (n + 31) / 32;
  fused_kernel<<<grid, 512, LDS_BYTES, stream>>>(x, wt, out, n);
}